// Round 5
// baseline (2056.946 us; speedup 1.0000x reference)
//
#include <hip/hip_runtime.h>

// Problem constants
#define NBATCH 8
#define SDIM   1024
#define DDIM   1024
#define NHEAD  16
#define DKDIM  64

typedef __attribute__((ext_vector_type(8))) short  short8;   // 8 bf16 (4 VGPR)
typedef __attribute__((ext_vector_type(4))) float  f32x4;    // MFMA acc

// round-to-nearest-even bf16 bits of x
__device__ __forceinline__ unsigned bf16rne(float x) {
    unsigned u = __float_as_uint(x);
    return (u + 0x7fffu + ((u >> 16) & 1u)) >> 16;
}

// 16B-slot XOR swizzle (T2 / §6 G4): spreads 8 consecutive rows across slots
#define SWZ(row, slot) ((slot) ^ ((row) & 7))

// ---------------------------------------------------------------------------
// proj_mfma: unchanged from R3 (~108us each, split-bf16 3-pass MFMA).
// ---------------------------------------------------------------------------
__global__ __launch_bounds__(256, 2)
void proj_mfma(const float* __restrict__ X, const float* __restrict__ W,
               const float* __restrict__ bias, float* __restrict__ Y,
               int head_layout)
{
    __shared__ unsigned short Ah[128 * 40], Al[128 * 40];
    __shared__ unsigned short Bh[128 * 40], Bl[128 * 40];

    const int t    = threadIdx.x;
    const int lane = t & 63, wid = t >> 6;
    const int wr   = wid >> 1, wc = wid & 1;
    const int lr   = lane & 15, lg = lane >> 4;

    const int flat    = blockIdx.x;
    const int logical = (flat & 7) * 64 + (flat >> 3);
    const int by = logical >> 3, bx = logical & 7;
    const int rbase = by << 7, cbase = bx << 7;

    f32x4 acc[4][4];
#pragma unroll
    for (int i = 0; i < 4; ++i)
#pragma unroll
        for (int j = 0; j < 4; ++j) acc[i][j] = (f32x4){0.f, 0.f, 0.f, 0.f};

    float4 aR[4];
    float  bR[4][4];

#define LOAD_TILE(KB)                                                          \
    {                                                                          \
        _Pragma("unroll")                                                      \
        for (int u = 0; u < 4; ++u) {                                          \
            int slot = t + (u << 8);                                           \
            int arow = slot >> 3, ac4 = slot & 7;                              \
            aR[u] = *(const float4*)(X + (size_t)(rbase + arow) * DDIM         \
                                       + (KB) + ac4 * 4);                      \
        }                                                                      \
        _Pragma("unroll")                                                      \
        for (int u = 0; u < 4; ++u) {                                          \
            int slot = t + (u << 8);                                           \
            int bn = slot & 127, k0 = (slot >> 7) << 2;                        \
            _Pragma("unroll")                                                  \
            for (int e = 0; e < 4; ++e)                                        \
                bR[u][e] = W[(size_t)((KB) + k0 + e) * DDIM + cbase + bn];     \
        }                                                                      \
    }

    LOAD_TILE(0)

    for (int kt = 0; kt < DDIM / 32; ++kt) {
#pragma unroll
        for (int u = 0; u < 4; ++u) {
            int slot = t + (u << 8);
            int arow = slot >> 3, ac4 = slot & 7;
            float4 v = aR[u];
            unsigned h0 = bf16rne(v.x), h1 = bf16rne(v.y),
                     h2 = bf16rne(v.z), h3 = bf16rne(v.w);
            float r0 = v.x - __uint_as_float(h0 << 16);
            float r1 = v.y - __uint_as_float(h1 << 16);
            float r2 = v.z - __uint_as_float(h2 << 16);
            float r3 = v.w - __uint_as_float(h3 << 16);
            uint2 hv, lv;
            hv.x = h0 | (h1 << 16);           hv.y = h2 | (h3 << 16);
            lv.x = bf16rne(r0) | (bf16rne(r1) << 16);
            lv.y = bf16rne(r2) | (bf16rne(r3) << 16);
            *(uint2*)&Ah[arow * 40 + ac4 * 4] = hv;
            *(uint2*)&Al[arow * 40 + ac4 * 4] = lv;
        }
#pragma unroll
        for (int u = 0; u < 4; ++u) {
            int slot = t + (u << 8);
            int bn = slot & 127, k0 = (slot >> 7) << 2;
            unsigned h[4], l[4];
#pragma unroll
            for (int e = 0; e < 4; ++e) {
                h[e] = bf16rne(bR[u][e]);
                l[e] = bf16rne(bR[u][e] - __uint_as_float(h[e] << 16));
            }
            uint2 hv, lv;
            hv.x = h[0] | (h[1] << 16);  hv.y = h[2] | (h[3] << 16);
            lv.x = l[0] | (l[1] << 16);  lv.y = l[2] | (l[3] << 16);
            *(uint2*)&Bh[bn * 40 + k0] = hv;
            *(uint2*)&Bl[bn * 40 + k0] = lv;
        }
        __syncthreads();

        if (kt < DDIM / 32 - 1) LOAD_TILE((kt + 1) << 5)

        short8 ah[4], al4[4], bh4[4], bl4[4];
#pragma unroll
        for (int i = 0; i < 4; ++i) {
            int row = wr * 64 + i * 16 + lr;
            ah[i]  = *(const short8*)&Ah[row * 40 + lg * 8];
            al4[i] = *(const short8*)&Al[row * 40 + lg * 8];
        }
#pragma unroll
        for (int j = 0; j < 4; ++j) {
            int col = wc * 64 + j * 16 + lr;
            bh4[j] = *(const short8*)&Bh[col * 40 + lg * 8];
            bl4[j] = *(const short8*)&Bl[col * 40 + lg * 8];
        }
#pragma unroll
        for (int i = 0; i < 4; ++i)
#pragma unroll
            for (int j = 0; j < 4; ++j) {
                acc[i][j] = __builtin_amdgcn_mfma_f32_16x16x32_bf16(
                    ah[i], bh4[j], acc[i][j], 0, 0, 0);
                acc[i][j] = __builtin_amdgcn_mfma_f32_16x16x32_bf16(
                    ah[i], bl4[j], acc[i][j], 0, 0, 0);
                acc[i][j] = __builtin_amdgcn_mfma_f32_16x16x32_bf16(
                    al4[i], bh4[j], acc[i][j], 0, 0, 0);
            }
        __syncthreads();
    }
#undef LOAD_TILE

#pragma unroll
    for (int j = 0; j < 4; ++j) {
        int gcol = cbase + wc * 64 + j * 16 + lr;
        float bv = bias[gcol];
        int h = gcol >> 6, dk = gcol & 63;
#pragma unroll
        for (int i = 0; i < 4; ++i) {
#pragma unroll
            for (int rr = 0; rr < 4; ++rr) {
                int grow = rbase + wr * 64 + i * 16 + lg * 4 + rr;
                float val = acc[i][j][rr] + bv;
                if (head_layout) {
                    int b = grow >> 10, s = grow & (SDIM - 1);
                    Y[(((size_t)(b * NHEAD + h) * SDIM + s) << 6) + dk] = val;
                } else {
                    Y[(size_t)grow * DDIM + gcol] = val;
                }
            }
        }
    }
}

// ---------------------------------------------------------------------------
// attn_mfma v2 (R5): occupancy + conflict + latency fixes vs R4.
//  - LDS: all bf16 buffers 128B rows + XOR-swizzle SWZ(row,slot), both sides.
//  - V staged as bf16 (Vsb) instead of fp32: LDS 46->49KB but (256,3)
//    launch bounds + 49KB => 3 blocks/CU (12 waves, was 7).
//  - mask/gp pre-staged into LDS (GsPm) with coalesced f4/i4 loads during the
//    K/V staging phase; value = allowed ? gp : -1.0 (bf16 sign trick).
//    Deferred masking is exact: row max over ALL scores >= true max, shift
//    cancels in p/l; masked get p*0 in PV and g<0 excludes them from l.
//  - GsPm buffer dual-use: gs(t) read pre-b2; pm(t) written post-b2;
//    gs(t+1) written post-b3. Phase-disjoint by barriers.
// Per tile: [b1] Vtranspose, QK(3-pass), softmax(gs) [b2] LOADKV(t+1),
//           pm-write, PV [b3] STOREKV+STAGEGS(t+1) [b1].
// ---------------------------------------------------------------------------
__global__ __launch_bounds__(256, 3)
void attn_mfma(const float* __restrict__ Qw, const float* __restrict__ Kw,
               const float* __restrict__ Vw, const float* __restrict__ gp,
               const int* __restrict__ mask, float* __restrict__ Xo)
{
    __shared__ unsigned short Kh[64 * 64], Kl[64 * 64];    // swizzled [k][d]
    __shared__ unsigned short Vt[64 * 64];                 // swizzled [d][k]
    __shared__ unsigned short Vsb[64 * 72];                // bf16 V [k][d]
    __shared__ unsigned short GsPm[128 * 64];              // gs / pm, swizzled

    const int t    = threadIdx.x;
    const int lane = t & 63, w = t >> 6;
    const int lr   = lane & 15, lg = lane >> 4;

    const int flat    = blockIdx.x;
    const int logical = (flat & 7) * 128 + (flat >> 3);
    const int bh = logical >> 3, qbi = logical & 7;
    const int b  = bh >> 4, h = bh & 15;
    const int qb0 = qbi << 7;

    const float* Qp = Qw + (size_t)bh * SDIM * DKDIM;
    const float* Kp = Kw + (size_t)bh * SDIM * DKDIM;
    const float* Vp = Vw + (size_t)bh * SDIM * DKDIM;

    // ---- Q fragments in registers (one-time) ----
    short8 qh[2][2], ql[2][2];
#pragma unroll
    for (int i = 0; i < 2; ++i)
#pragma unroll
        for (int kk = 0; kk < 2; ++kk) {
            const float* src = Qp + (size_t)(qb0 + w * 32 + i * 16 + lr) * DKDIM
                                  + kk * 32 + lg * 8;
            float4 a = *(const float4*)src;
            float4 c = *(const float4*)(src + 4);
            float f[8] = {a.x, a.y, a.z, a.w, c.x, c.y, c.z, c.w};
            short8 hh, ll;
#pragma unroll
            for (int e = 0; e < 8; ++e) {
                unsigned hb = bf16rne(f[e]);
                hh[e] = (short)hb;
                ll[e] = (short)bf16rne(f[e] - __uint_as_float(hb << 16));
            }
            qh[i][kk] = hh; ql[i][kk] = ll;
        }

    float mreg[8], lreg[8];
    f32x4 pv[2][4];
#pragma unroll
    for (int r = 0; r < 8; ++r) { mreg[r] = -3.0e38f; lreg[r] = 0.f; }
#pragma unroll
    for (int i = 0; i < 2; ++i)
#pragma unroll
        for (int j = 0; j < 4; ++j) pv[i][j] = (f32x4){0.f, 0.f, 0.f, 0.f};

    float4 kst[4], vst[4];

#define LOADKV(KB)                                                             \
    {                                                                          \
        _Pragma("unroll")                                                      \
        for (int u = 0; u < 4; ++u) {                                          \
            int slot = t + (u << 8);                                           \
            int krow = slot >> 4, f4i = slot & 15;                             \
            kst[u] = *(const float4*)(Kp + (size_t)((KB) + krow) * DKDIM + f4i * 4); \
            vst[u] = *(const float4*)(Vp + (size_t)((KB) + krow) * DKDIM + f4i * 4); \
        }                                                                      \
    }

#define STOREKV()                                                              \
    {                                                                          \
        _Pragma("unroll")                                                      \
        for (int u = 0; u < 4; ++u) {                                          \
            int slot = t + (u << 8);                                           \
            int krow = slot >> 4, f4i = slot & 15;                             \
            float f[4] = {kst[u].x, kst[u].y, kst[u].z, kst[u].w};             \
            unsigned hb[4], lb[4];                                             \
            _Pragma("unroll")                                                  \
            for (int e = 0; e < 4; ++e) {                                      \
                hb[e] = bf16rne(f[e]);                                         \
                lb[e] = bf16rne(f[e] - __uint_as_float(hb[e] << 16));          \
            }                                                                  \
            uint2 hv, lv;                                                      \
            hv.x = hb[0] | (hb[1] << 16); hv.y = hb[2] | (hb[3] << 16);        \
            lv.x = lb[0] | (lb[1] << 16); lv.y = lb[2] | (lb[3] << 16);        \
            int ko = krow * 64 + SWZ(krow, f4i >> 1) * 8 + (f4i & 1) * 4;      \
            *(uint2*)&Kh[ko] = hv;                                             \
            *(uint2*)&Kl[ko] = lv;                                             \
            unsigned vb0 = bf16rne(vst[u].x), vb1 = bf16rne(vst[u].y);         \
            unsigned vb2 = bf16rne(vst[u].z), vb3 = bf16rne(vst[u].w);         \
            uint2 vv; vv.x = vb0 | (vb1 << 16); vv.y = vb2 | (vb3 << 16);      \
            *(uint2*)&Vsb[krow * 72 + f4i * 4] = vv;                           \
        }                                                                      \
    }

    // gs: [q 0..127][k 0..63] bf16; allowed ? gp : -1.0  (0xBF80)
#define STAGEGS(KB)                                                            \
    {                                                                          \
        _Pragma("unroll")                                                      \
        for (int u = 0; u < 8; ++u) {                                          \
            int slot = t + (u << 8);                                           \
            int row = slot >> 4, c4 = slot & 15;                               \
            int qrow = qb0 + row;                                              \
            size_t base = ((size_t)b * SDIM + qrow) * SDIM + (KB) + c4 * 4;    \
            float4 g4 = *(const float4*)(gp + base);                           \
            int4   m4 = *(const int4*)(mask + base);                           \
            int kc = (KB) + c4 * 4;                                            \
            unsigned o0 = ((m4.x != 0) || (qrow == kc + 0)) ? bf16rne(g4.x) : 0xBF80u; \
            unsigned o1 = ((m4.y != 0) || (qrow == kc + 1)) ? bf16rne(g4.y) : 0xBF80u; \
            unsigned o2 = ((m4.z != 0) || (qrow == kc + 2)) ? bf16rne(g4.z) : 0xBF80u; \
            unsigned o3 = ((m4.w != 0) || (qrow == kc + 3)) ? bf16rne(g4.w) : 0xBF80u; \
            uint2 ov; ov.x = o0 | (o1 << 16); ov.y = o2 | (o3 << 16);          \
            *(uint2*)&GsPm[row * 64 + SWZ(row, c4 >> 1) * 8 + (c4 & 1) * 4] = ov; \
        }                                                                      \
    }

    LOADKV(0)
    STOREKV()
    STAGEGS(0)
    __syncthreads();                               // tile 0 staged

    for (int kt = 0; kt < SDIM / 64; ++kt) {
        const int kbase = kt << 6;

        // ---- V transpose: Vsb bf16 [k][d] -> Vt swizzled [d][k] ----
        {
            const int c = t & 63, k0 = (t >> 6) << 4;
            unsigned short vtmp[16];
#pragma unroll
            for (int e = 0; e < 16; ++e)
                vtmp[e] = Vsb[(k0 + e) * 72 + c];
            uint4 w0, w1;
            w0.x = vtmp[0]  | ((unsigned)vtmp[1]  << 16);
            w0.y = vtmp[2]  | ((unsigned)vtmp[3]  << 16);
            w0.z = vtmp[4]  | ((unsigned)vtmp[5]  << 16);
            w0.w = vtmp[6]  | ((unsigned)vtmp[7]  << 16);
            w1.x = vtmp[8]  | ((unsigned)vtmp[9]  << 16);
            w1.y = vtmp[10] | ((unsigned)vtmp[11] << 16);
            w1.z = vtmp[12] | ((unsigned)vtmp[13] << 16);
            w1.w = vtmp[14] | ((unsigned)vtmp[15] << 16);
            int s0 = k0 >> 3;                      // = 2*w
            *(uint4*)&Vt[c * 64 + SWZ(c, s0)     * 8] = w0;
            *(uint4*)&Vt[c * 64 + SWZ(c, s0 + 1) * 8] = w1;
        }

        // ---- QK^T: 3-pass split-bf16 ----
        f32x4 sc[2][4];
#pragma unroll
        for (int i = 0; i < 2; ++i)
#pragma unroll
            for (int j = 0; j < 4; ++j) sc[i][j] = (f32x4){0.f, 0.f, 0.f, 0.f};
#pragma unroll
        for (int kk = 0; kk < 2; ++kk) {
            short8 bh8[4], bl8[4];
#pragma unroll
            for (int j = 0; j < 4; ++j) {
                int R = j * 16 + lr;
                int off = R * 64 + SWZ(R, kk * 4 + lg) * 8;
                bh8[j] = *(const short8*)&Kh[off];
                bl8[j] = *(const short8*)&Kl[off];
            }
#pragma unroll
            for (int i = 0; i < 2; ++i)
#pragma unroll
                for (int j = 0; j < 4; ++j) {
                    sc[i][j] = __builtin_amdgcn_mfma_f32_16x16x32_bf16(
                        qh[i][kk], bh8[j], sc[i][j], 0, 0, 0);
                    sc[i][j] = __builtin_amdgcn_mfma_f32_16x16x32_bf16(
                        qh[i][kk], bl8[j], sc[i][j], 0, 0, 0);
                    sc[i][j] = __builtin_amdgcn_mfma_f32_16x16x32_bf16(
                        ql[i][kk], bh8[j], sc[i][j], 0, 0, 0);
                }
        }

        // ---- softmax (deferred mask via gs sign trick) ----
        unsigned short pmv[2][4][4];
#pragma unroll
        for (int i = 0; i < 2; ++i) {
#pragma unroll
            for (int rr = 0; rr < 4; ++rr) {
                const int row64 = w * 32 + i * 16 + lg * 4 + rr;
                float sv[4];
#pragma unroll
                for (int j = 0; j < 4; ++j) sv[j] = sc[i][j][rr] * 0.125f;
                float tm = fmaxf(fmaxf(sv[0], sv[1]), fmaxf(sv[2], sv[3]));
#pragma unroll
                for (int off = 1; off < 16; off <<= 1)
                    tm = fmaxf(tm, __shfl_xor(tm, off));
                const int r = i * 4 + rr;
                float mn  = fmaxf(mreg[r], tm);
                float fac = __expf(mreg[r] - mn);  // first tile: 0
                float ts = 0.f;
#pragma unroll
                for (int j = 0; j < 4; ++j) {
                    float pj = __expf(sv[j] - mn);
                    int go = row64 * 64 + SWZ(row64, 2 * j + (lr >> 3)) * 8 + (lr & 7);
                    float g = __uint_as_float((unsigned)GsPm[go] << 16);
                    ts += (g >= 0.f) ? pj : 0.f;   // l: gp NOT included
                    pmv[i][rr][j] = (unsigned short)bf16rne(pj * fmaxf(g, 0.f));
                }
#pragma unroll
                for (int off = 1; off < 16; off <<= 1)
                    ts += __shfl_xor(ts, off);
                lreg[r] = lreg[r] * fac + ts;
                mreg[r] = mn;
#pragma unroll
                for (int j = 0; j < 4; ++j) pv[i][j][rr] *= fac;
            }
        }

        __syncthreads();                           // b2: gs reads done, Vt ready

        if (kt < SDIM / 64 - 1) LOADKV(kbase + 64) // prefetch under PV

        // ---- write P*gp into GsPm (own wave's rows; same-wave DS order) ----
#pragma unroll
        for (int i = 0; i < 2; ++i)
#pragma unroll
            for (int rr = 0; rr < 4; ++rr) {
                int row = w * 32 + i * 16 + lg * 4 + rr;
#pragma unroll
                for (int j = 0; j < 4; ++j)
                    GsPm[row * 64 + SWZ(row, 2 * j + (lr >> 3)) * 8 + (lr & 7)]
                        = pmv[i][rr][j];
            }

        // ---- PV: single-pass bf16 ----
#pragma unroll
        for (int kk = 0; kk < 2; ++kk) {
            short8 pa[2], vb[4];
#pragma unroll
            for (int i = 0; i < 2; ++i) {
                int rowp = w * 32 + i * 16 + lr;
                pa[i] = *(const short8*)&GsPm[rowp * 64 + SWZ(rowp, kk * 4 + lg) * 8];
            }
#pragma unroll
            for (int j = 0; j < 4; ++j) {
                int R = j * 16 + lr;
                vb[j] = *(const short8*)&Vt[R * 64 + SWZ(R, kk * 4 + lg) * 8];
            }
#pragma unroll
            for (int i = 0; i < 2; ++i)
#pragma unroll
                for (int j = 0; j < 4; ++j)
                    pv[i][j] = __builtin_amdgcn_mfma_f32_16x16x32_bf16(
                        pa[i], vb[j], pv[i][j], 0, 0, 0);
        }

        __syncthreads();                           // b3: PV reads done

        if (kt < SDIM / 64 - 1) {
            STOREKV()
            STAGEGS(kbase + 64)
            __syncthreads();                       // b1: next tile staged
        }
    }
#undef LOADKV
#undef STOREKV
#undef STAGEGS

    // ---- epilogue: out = pv / l ----
#pragma unroll
    for (int i = 0; i < 2; ++i)
#pragma unroll
        for (int rr = 0; rr < 4; ++rr) {
            int qrow  = qb0 + w * 32 + i * 16 + lg * 4 + rr;
            float inv = 1.f / lreg[i * 4 + rr];
            float* orow = Xo + ((size_t)b * SDIM + qrow) * DDIM + h * DKDIM;
#pragma unroll
            for (int j = 0; j < 4; ++j)
                orow[j * 16 + lr] = pv[i][j][rr] * inv;
        }
}

// ---------------------------------------------------------------------------
extern "C" void kernel_launch(void* const* d_in, const int* in_sizes, int n_in,
                              void* d_out, int out_size, void* d_ws, size_t ws_size,
                              hipStream_t stream)
{
    (void)in_sizes; (void)n_in; (void)out_size; (void)ws_size;
    const float* query = (const float*)d_in[0];
    const float* key_  = (const float*)d_in[1];
    const float* value = (const float*)d_in[2];
    const float* gp    = (const float*)d_in[3];
    const int*   mask  = (const int*)d_in[4];
    const float* Wq = (const float*)d_in[5];  const float* bq = (const float*)d_in[6];
    const float* Wk = (const float*)d_in[7];  const float* bk = (const float*)d_in[8];
    const float* Wv = (const float*)d_in[9];  const float* bv = (const float*)d_in[10];
    const float* Wo = (const float*)d_in[11]; const float* bo = (const float*)d_in[12];
    float* out = (float*)d_out;

    const size_t NE = (size_t)NBATCH * SDIM * DDIM;   // 8.39M floats each
    float* Qw = (float*)d_ws;          // [B,H,S,DK]
    float* Kw = Qw + NE;
    float* Vw = Kw + NE;
    float* Xo = Vw + NE;               // [B,S,D]  (ws total: 134 MB)

    dim3 blk(256);
    dim3 gproj(512);                                  // 128x128 tiles, swizzled
    hipLaunchKernelGGL(proj_mfma, gproj, blk, 0, stream, query, Wq, bq, Qw, 1);
    hipLaunchKernelGGL(proj_mfma, gproj, blk, 0, stream, key_,  Wk, bk, Kw, 1);
    hipLaunchKernelGGL(proj_mfma, gproj, blk, 0, stream, value, Wv, bv, Vw, 1);
    dim3 gattn(NBATCH * NHEAD * (SDIM / 128));        // 1024, XCD-swizzled
    hipLaunchKernelGGL(attn_mfma, gattn, blk, 0, stream, Qw, Kw, Vw, gp, mask, Xo);
    hipLaunchKernelGGL(proj_mfma, gproj, blk, 0, stream, Xo, Wo, bo, out, 0);
}

// Round 7
// 991.681 us; speedup vs baseline: 2.0742x; 2.0742x over previous
//
#include <hip/hip_runtime.h>

// Problem constants
#define NBATCH 8
#define SDIM   1024
#define DDIM   1024
#define NHEAD  16
#define DKDIM  64

typedef __attribute__((ext_vector_type(8))) short  short8;   // 8 bf16 (4 VGPR)
typedef __attribute__((ext_vector_type(4))) float  f32x4;    // MFMA acc

// round-to-nearest-even bf16 bits of x
__device__ __forceinline__ unsigned bf16rne(float x) {
    unsigned u = __float_as_uint(x);
    return (u + 0x7fffu + ((u >> 16) & 1u)) >> 16;
}

// 16B-slot XOR swizzle (T2 / §6 G4): spreads 8 consecutive rows across slots
#define SWZ(row, slot) ((slot) ^ ((row) & 7))

// ---------------------------------------------------------------------------
// proj_mfma: unchanged from R3 (~108us each, split-bf16 3-pass MFMA).
// NOTE empirical launch_bounds map on this compiler: arg N -> VGPR cap
// ~512/(2N). (256,2)=128 cap, fits; do NOT raise N (R5 lesson: spills).
// ---------------------------------------------------------------------------
__global__ __launch_bounds__(256, 2)
void proj_mfma(const float* __restrict__ X, const float* __restrict__ W,
               const float* __restrict__ bias, float* __restrict__ Y,
               int head_layout)
{
    __shared__ unsigned short Ah[128 * 40], Al[128 * 40];
    __shared__ unsigned short Bh[128 * 40], Bl[128 * 40];

    const int t    = threadIdx.x;
    const int lane = t & 63, wid = t >> 6;
    const int wr   = wid >> 1, wc = wid & 1;
    const int lr   = lane & 15, lg = lane >> 4;

    const int flat    = blockIdx.x;
    const int logical = (flat & 7) * 64 + (flat >> 3);
    const int by = logical >> 3, bx = logical & 7;
    const int rbase = by << 7, cbase = bx << 7;

    f32x4 acc[4][4];
#pragma unroll
    for (int i = 0; i < 4; ++i)
#pragma unroll
        for (int j = 0; j < 4; ++j) acc[i][j] = (f32x4){0.f, 0.f, 0.f, 0.f};

    float4 aR[4];
    float  bR[4][4];

#define LOAD_TILE(KB)                                                          \
    {                                                                          \
        _Pragma("unroll")                                                      \
        for (int u = 0; u < 4; ++u) {                                          \
            int slot = t + (u << 8);                                           \
            int arow = slot >> 3, ac4 = slot & 7;                              \
            aR[u] = *(const float4*)(X + (size_t)(rbase + arow) * DDIM         \
                                       + (KB) + ac4 * 4);                      \
        }                                                                      \
        _Pragma("unroll")                                                      \
        for (int u = 0; u < 4; ++u) {                                          \
            int slot = t + (u << 8);                                           \
            int bn = slot & 127, k0 = (slot >> 7) << 2;                        \
            _Pragma("unroll")                                                  \
            for (int e = 0; e < 4; ++e)                                        \
                bR[u][e] = W[(size_t)((KB) + k0 + e) * DDIM + cbase + bn];     \
        }                                                                      \
    }

    LOAD_TILE(0)

    for (int kt = 0; kt < DDIM / 32; ++kt) {
#pragma unroll
        for (int u = 0; u < 4; ++u) {
            int slot = t + (u << 8);
            int arow = slot >> 3, ac4 = slot & 7;
            float4 v = aR[u];
            unsigned h0 = bf16rne(v.x), h1 = bf16rne(v.y),
                     h2 = bf16rne(v.z), h3 = bf16rne(v.w);
            float r0 = v.x - __uint_as_float(h0 << 16);
            float r1 = v.y - __uint_as_float(h1 << 16);
            float r2 = v.z - __uint_as_float(h2 << 16);
            float r3 = v.w - __uint_as_float(h3 << 16);
            uint2 hv, lv;
            hv.x = h0 | (h1 << 16);           hv.y = h2 | (h3 << 16);
            lv.x = bf16rne(r0) | (bf16rne(r1) << 16);
            lv.y = bf16rne(r2) | (bf16rne(r3) << 16);
            *(uint2*)&Ah[arow * 40 + ac4 * 4] = hv;
            *(uint2*)&Al[arow * 40 + ac4 * 4] = lv;
        }
#pragma unroll
        for (int u = 0; u < 4; ++u) {
            int slot = t + (u << 8);
            int bn = slot & 127, k0 = (slot >> 7) << 2;
            unsigned h[4], l[4];
#pragma unroll
            for (int e = 0; e < 4; ++e) {
                h[e] = bf16rne(bR[u][e]);
                l[e] = bf16rne(bR[u][e] - __uint_as_float(h[e] << 16));
            }
            uint2 hv, lv;
            hv.x = h[0] | (h[1] << 16);  hv.y = h[2] | (h[3] << 16);
            lv.x = l[0] | (l[1] << 16);  lv.y = l[2] | (l[3] << 16);
            *(uint2*)&Bh[bn * 40 + k0] = hv;
            *(uint2*)&Bl[bn * 40 + k0] = lv;
        }
        __syncthreads();

        if (kt < DDIM / 32 - 1) LOAD_TILE((kt + 1) << 5)

        short8 ah[4], al4[4], bh4[4], bl4[4];
#pragma unroll
        for (int i = 0; i < 4; ++i) {
            int row = wr * 64 + i * 16 + lr;
            ah[i]  = *(const short8*)&Ah[row * 40 + lg * 8];
            al4[i] = *(const short8*)&Al[row * 40 + lg * 8];
        }
#pragma unroll
        for (int j = 0; j < 4; ++j) {
            int col = wc * 64 + j * 16 + lr;
            bh4[j] = *(const short8*)&Bh[col * 40 + lg * 8];
            bl4[j] = *(const short8*)&Bl[col * 40 + lg * 8];
        }
#pragma unroll
        for (int i = 0; i < 4; ++i)
#pragma unroll
            for (int j = 0; j < 4; ++j) {
                acc[i][j] = __builtin_amdgcn_mfma_f32_16x16x32_bf16(
                    ah[i], bh4[j], acc[i][j], 0, 0, 0);
                acc[i][j] = __builtin_amdgcn_mfma_f32_16x16x32_bf16(
                    ah[i], bl4[j], acc[i][j], 0, 0, 0);
                acc[i][j] = __builtin_amdgcn_mfma_f32_16x16x32_bf16(
                    al4[i], bh4[j], acc[i][j], 0, 0, 0);
            }
        __syncthreads();
    }
#undef LOAD_TILE

#pragma unroll
    for (int j = 0; j < 4; ++j) {
        int gcol = cbase + wc * 64 + j * 16 + lr;
        float bv = bias[gcol];
        int h = gcol >> 6, dk = gcol & 63;
#pragma unroll
        for (int i = 0; i < 4; ++i) {
#pragma unroll
            for (int rr = 0; rr < 4; ++rr) {
                int grow = rbase + wr * 64 + i * 16 + lg * 4 + rr;
                float val = acc[i][j][rr] + bv;
                if (head_layout) {
                    int b = grow >> 10, s = grow & (SDIM - 1);
                    Y[(((size_t)(b * NHEAD + h) * SDIM + s) << 6) + dk] = val;
                } else {
                    Y[(size_t)grow * DDIM + gcol] = val;
                }
            }
        }
    }
}

// ---------------------------------------------------------------------------
// attn_mfma v3 (R6 resubmit) = R5 structure with __launch_bounds__(256,1).
// R5 lesson: arg 3 -> VGPR cap 84 -> 3.9GB spill traffic, 3.6x slower.
// arg 1 -> cap 256; kernel needs ~200 live VGPRs -> no spill; 2 blocks/CU
// (LDS 49KB, VGPR<=256 -> 2 waves/SIMD).
// Keeps R5's verified wins: zero bank conflicts (XOR swizzle both sides),
// mask/gp pre-staged coalesced (deferred-mask sign trick, exact), T14
// K/V prefetch under PV.
// ---------------------------------------------------------------------------
__global__ __launch_bounds__(256, 1)
void attn_mfma(const float* __restrict__ Qw, const float* __restrict__ Kw,
               const float* __restrict__ Vw, const float* __restrict__ gp,
               const int* __restrict__ mask, float* __restrict__ Xo)
{
    __shared__ unsigned short Kh[64 * 64], Kl[64 * 64];    // swizzled [k][d]
    __shared__ unsigned short Vt[64 * 64];                 // swizzled [d][k]
    __shared__ unsigned short Vsb[64 * 72];                // bf16 V [k][d]
    __shared__ unsigned short GsPm[128 * 64];              // gs / pm, swizzled

    const int t    = threadIdx.x;
    const int lane = t & 63, w = t >> 6;
    const int lr   = lane & 15, lg = lane >> 4;

    const int flat    = blockIdx.x;
    const int logical = (flat & 7) * 128 + (flat >> 3);
    const int bh = logical >> 3, qbi = logical & 7;
    const int b  = bh >> 4, h = bh & 15;
    const int qb0 = qbi << 7;

    const float* Qp = Qw + (size_t)bh * SDIM * DKDIM;
    const float* Kp = Kw + (size_t)bh * SDIM * DKDIM;
    const float* Vp = Vw + (size_t)bh * SDIM * DKDIM;

    // ---- Q fragments in registers (one-time) ----
    short8 qh[2][2], ql[2][2];
#pragma unroll
    for (int i = 0; i < 2; ++i)
#pragma unroll
        for (int kk = 0; kk < 2; ++kk) {
            const float* src = Qp + (size_t)(qb0 + w * 32 + i * 16 + lr) * DKDIM
                                  + kk * 32 + lg * 8;
            float4 a = *(const float4*)src;
            float4 c = *(const float4*)(src + 4);
            float f[8] = {a.x, a.y, a.z, a.w, c.x, c.y, c.z, c.w};
            short8 hh, ll;
#pragma unroll
            for (int e = 0; e < 8; ++e) {
                unsigned hb = bf16rne(f[e]);
                hh[e] = (short)hb;
                ll[e] = (short)bf16rne(f[e] - __uint_as_float(hb << 16));
            }
            qh[i][kk] = hh; ql[i][kk] = ll;
        }

    float mreg[8], lreg[8];
    f32x4 pv[2][4];
#pragma unroll
    for (int r = 0; r < 8; ++r) { mreg[r] = -3.0e38f; lreg[r] = 0.f; }
#pragma unroll
    for (int i = 0; i < 2; ++i)
#pragma unroll
        for (int j = 0; j < 4; ++j) pv[i][j] = (f32x4){0.f, 0.f, 0.f, 0.f};

    float4 kst[4], vst[4];

#define LOADKV(KB)                                                             \
    {                                                                          \
        _Pragma("unroll")                                                      \
        for (int u = 0; u < 4; ++u) {                                          \
            int slot = t + (u << 8);                                           \
            int krow = slot >> 4, f4i = slot & 15;                             \
            kst[u] = *(const float4*)(Kp + (size_t)((KB) + krow) * DKDIM + f4i * 4); \
            vst[u] = *(const float4*)(Vp + (size_t)((KB) + krow) * DKDIM + f4i * 4); \
        }                                                                      \
    }

#define STOREKV()                                                              \
    {                                                                          \
        _Pragma("unroll")                                                      \
        for (int u = 0; u < 4; ++u) {                                          \
            int slot = t + (u << 8);                                           \
            int krow = slot >> 4, f4i = slot & 15;                             \
            float f[4] = {kst[u].x, kst[u].y, kst[u].z, kst[u].w};             \
            unsigned hb[4], lb[4];                                             \
            _Pragma("unroll")                                                  \
            for (int e = 0; e < 4; ++e) {                                      \
                hb[e] = bf16rne(f[e]);                                         \
                lb[e] = bf16rne(f[e] - __uint_as_float(hb[e] << 16));          \
            }                                                                  \
            uint2 hv, lv;                                                      \
            hv.x = hb[0] | (hb[1] << 16); hv.y = hb[2] | (hb[3] << 16);        \
            lv.x = lb[0] | (lb[1] << 16); lv.y = lb[2] | (lb[3] << 16);        \
            int ko = krow * 64 + SWZ(krow, f4i >> 1) * 8 + (f4i & 1) * 4;      \
            *(uint2*)&Kh[ko] = hv;                                             \
            *(uint2*)&Kl[ko] = lv;                                             \
            unsigned vb0 = bf16rne(vst[u].x), vb1 = bf16rne(vst[u].y);         \
            unsigned vb2 = bf16rne(vst[u].z), vb3 = bf16rne(vst[u].w);         \
            uint2 vv; vv.x = vb0 | (vb1 << 16); vv.y = vb2 | (vb3 << 16);      \
            *(uint2*)&Vsb[krow * 72 + f4i * 4] = vv;                           \
        }                                                                      \
    }

    // gs: [q 0..127][k 0..63] bf16; allowed ? gp : -1.0  (0xBF80)
#define STAGEGS(KB)                                                            \
    {                                                                          \
        _Pragma("unroll")                                                      \
        for (int u = 0; u < 8; ++u) {                                          \
            int slot = t + (u << 8);                                           \
            int row = slot >> 4, c4 = slot & 15;                               \
            int qrow = qb0 + row;                                              \
            size_t base = ((size_t)b * SDIM + qrow) * SDIM + (KB) + c4 * 4;    \
            float4 g4 = *(const float4*)(gp + base);                           \
            int4   m4 = *(const int4*)(mask + base);                           \
            int kc = (KB) + c4 * 4;                                            \
            unsigned o0 = ((m4.x != 0) || (qrow == kc + 0)) ? bf16rne(g4.x) : 0xBF80u; \
            unsigned o1 = ((m4.y != 0) || (qrow == kc + 1)) ? bf16rne(g4.y) : 0xBF80u; \
            unsigned o2 = ((m4.z != 0) || (qrow == kc + 2)) ? bf16rne(g4.z) : 0xBF80u; \
            unsigned o3 = ((m4.w != 0) || (qrow == kc + 3)) ? bf16rne(g4.w) : 0xBF80u; \
            uint2 ov; ov.x = o0 | (o1 << 16); ov.y = o2 | (o3 << 16);          \
            *(uint2*)&GsPm[row * 64 + SWZ(row, c4 >> 1) * 8 + (c4 & 1) * 4] = ov; \
        }                                                                      \
    }

    LOADKV(0)
    STOREKV()
    STAGEGS(0)
    __syncthreads();                               // tile 0 staged

    for (int kt = 0; kt < SDIM / 64; ++kt) {
        const int kbase = kt << 6;

        // ---- V transpose: Vsb bf16 [k][d] -> Vt swizzled [d][k] ----
        {
            const int c = t & 63, k0 = (t >> 6) << 4;
            unsigned short vtmp[16];
#pragma unroll
            for (int e = 0; e < 16; ++e)
                vtmp[e] = Vsb[(k0 + e) * 72 + c];
            uint4 w0, w1;
            w0.x = vtmp[0]  | ((unsigned)vtmp[1]  << 16);
            w0.y = vtmp[2]  | ((unsigned)vtmp[3]  << 16);
            w0.z = vtmp[4]  | ((unsigned)vtmp[5]  << 16);
            w0.w = vtmp[6]  | ((unsigned)vtmp[7]  << 16);
            w1.x = vtmp[8]  | ((unsigned)vtmp[9]  << 16);
            w1.y = vtmp[10] | ((unsigned)vtmp[11] << 16);
            w1.z = vtmp[12] | ((unsigned)vtmp[13] << 16);
            w1.w = vtmp[14] | ((unsigned)vtmp[15] << 16);
            int s0 = k0 >> 3;                      // = 2*w
            *(uint4*)&Vt[c * 64 + SWZ(c, s0)     * 8] = w0;
            *(uint4*)&Vt[c * 64 + SWZ(c, s0 + 1) * 8] = w1;
        }

        // ---- QK^T: 3-pass split-bf16 ----
        f32x4 sc[2][4];
#pragma unroll
        for (int i = 0; i < 2; ++i)
#pragma unroll
            for (int j = 0; j < 4; ++j) sc[i][j] = (f32x4){0.f, 0.f, 0.f, 0.f};
#pragma unroll
        for (int kk = 0; kk < 2; ++kk) {
            short8 bh8[4], bl8[4];
#pragma unroll
            for (int j = 0; j < 4; ++j) {
                int R = j * 16 + lr;
                int off = R * 64 + SWZ(R, kk * 4 + lg) * 8;
                bh8[j] = *(const short8*)&Kh[off];
                bl8[j] = *(const short8*)&Kl[off];
            }
#pragma unroll
            for (int i = 0; i < 2; ++i)
#pragma unroll
                for (int j = 0; j < 4; ++j) {
                    sc[i][j] = __builtin_amdgcn_mfma_f32_16x16x32_bf16(
                        qh[i][kk], bh8[j], sc[i][j], 0, 0, 0);
                    sc[i][j] = __builtin_amdgcn_mfma_f32_16x16x32_bf16(
                        qh[i][kk], bl8[j], sc[i][j], 0, 0, 0);
                    sc[i][j] = __builtin_amdgcn_mfma_f32_16x16x32_bf16(
                        ql[i][kk], bh8[j], sc[i][j], 0, 0, 0);
                }
        }

        // ---- softmax (deferred mask via gs sign trick) ----
        unsigned short pmv[2][4][4];
#pragma unroll
        for (int i = 0; i < 2; ++i) {
#pragma unroll
            for (int rr = 0; rr < 4; ++rr) {
                const int row64 = w * 32 + i * 16 + lg * 4 + rr;
                float sv[4];
#pragma unroll
                for (int j = 0; j < 4; ++j) sv[j] = sc[i][j][rr] * 0.125f;
                float tm = fmaxf(fmaxf(sv[0], sv[1]), fmaxf(sv[2], sv[3]));
#pragma unroll
                for (int off = 1; off < 16; off <<= 1)
                    tm = fmaxf(tm, __shfl_xor(tm, off));
                const int r = i * 4 + rr;
                float mn  = fmaxf(mreg[r], tm);
                float fac = __expf(mreg[r] - mn);  // first tile: 0
                float ts = 0.f;
#pragma unroll
                for (int j = 0; j < 4; ++j) {
                    float pj = __expf(sv[j] - mn);
                    int go = row64 * 64 + SWZ(row64, 2 * j + (lr >> 3)) * 8 + (lr & 7);
                    float g = __uint_as_float((unsigned)GsPm[go] << 16);
                    ts += (g >= 0.f) ? pj : 0.f;   // l: gp NOT included
                    pmv[i][rr][j] = (unsigned short)bf16rne(pj * fmaxf(g, 0.f));
                }
#pragma unroll
                for (int off = 1; off < 16; off <<= 1)
                    ts += __shfl_xor(ts, off);
                lreg[r] = lreg[r] * fac + ts;
                mreg[r] = mn;
#pragma unroll
                for (int j = 0; j < 4; ++j) pv[i][j][rr] *= fac;
            }
        }

        __syncthreads();                           // b2: gs reads done, Vt ready

        if (kt < SDIM / 64 - 1) LOADKV(kbase + 64) // prefetch under PV

        // ---- write P*gp into GsPm (own wave's rows; same-wave DS order) ----
#pragma unroll
        for (int i = 0; i < 2; ++i)
#pragma unroll
            for (int rr = 0; rr < 4; ++rr) {
                int row = w * 32 + i * 16 + lg * 4 + rr;
#pragma unroll
                for (int j = 0; j < 4; ++j)
                    GsPm[row * 64 + SWZ(row, 2 * j + (lr >> 3)) * 8 + (lr & 7)]
                        = pmv[i][rr][j];
            }

        // ---- PV: single-pass bf16 ----
#pragma unroll
        for (int kk = 0; kk < 2; ++kk) {
            short8 pa[2], vb[4];
#pragma unroll
            for (int i = 0; i < 2; ++i) {
                int rowp = w * 32 + i * 16 + lr;
                pa[i] = *(const short8*)&GsPm[rowp * 64 + SWZ(rowp, kk * 4 + lg) * 8];
            }
#pragma unroll
            for (int j = 0; j < 4; ++j) {
                int R = j * 16 + lr;
                vb[j] = *(const short8*)&Vt[R * 64 + SWZ(R, kk * 4 + lg) * 8];
            }
#pragma unroll
            for (int i = 0; i < 2; ++i)
#pragma unroll
                for (int j = 0; j < 4; ++j)
                    pv[i][j] = __builtin_amdgcn_mfma_f32_16x16x32_bf16(
                        pa[i], vb[j], pv[i][j], 0, 0, 0);
        }

        __syncthreads();                           // b3: PV reads done

        if (kt < SDIM / 64 - 1) {
            STOREKV()
            STAGEGS(kbase + 64)
            __syncthreads();                       // b1: next tile staged
        }
    }
#undef LOADKV
#undef STOREKV
#undef STAGEGS

    // ---- epilogue: out = pv / l ----
#pragma unroll
    for (int i = 0; i < 2; ++i)
#pragma unroll
        for (int rr = 0; rr < 4; ++rr) {
            int qrow  = qb0 + w * 32 + i * 16 + lg * 4 + rr;
            float inv = 1.f / lreg[i * 4 + rr];
            float* orow = Xo + ((size_t)b * SDIM + qrow) * DDIM + h * DKDIM;
#pragma unroll
            for (int j = 0; j < 4; ++j)
                orow[j * 16 + lr] = pv[i][j][rr] * inv;
        }
}

// ---------------------------------------------------------------------------
extern "C" void kernel_launch(void* const* d_in, const int* in_sizes, int n_in,
                              void* d_out, int out_size, void* d_ws, size_t ws_size,
                              hipStream_t stream)
{
    (void)in_sizes; (void)n_in; (void)out_size; (void)ws_size;
    const float* query = (const float*)d_in[0];
    const float* key_  = (const float*)d_in[1];
    const float* value = (const float*)d_in[2];
    const float* gp    = (const float*)d_in[3];
    const int*   mask  = (const int*)d_in[4];
    const float* Wq = (const float*)d_in[5];  const float* bq = (const float*)d_in[6];
    const float* Wk = (const float*)d_in[7];  const float* bk = (const float*)d_in[8];
    const float* Wv = (const float*)d_in[9];  const float* bv = (const float*)d_in[10];
    const float* Wo = (const float*)d_in[11]; const float* bo = (const float*)d_in[12];
    float* out = (float*)d_out;

    const size_t NE = (size_t)NBATCH * SDIM * DDIM;   // 8.39M floats each
    float* Qw = (float*)d_ws;          // [B,H,S,DK]
    float* Kw = Qw + NE;
    float* Vw = Kw + NE;
    float* Xo = Vw + NE;               // [B,S,D]  (ws total: 134 MB)

    dim3 blk(256);
    dim3 gproj(512);                                  // 128x128 tiles, swizzled
    hipLaunchKernelGGL(proj_mfma, gproj, blk, 0, stream, query, Wq, bq, Qw, 1);
    hipLaunchKernelGGL(proj_mfma, gproj, blk, 0, stream, key_,  Wk, bk, Kw, 1);
    hipLaunchKernelGGL(proj_mfma, gproj, blk, 0, stream, value, Wv, bv, Vw, 1);
    dim3 gattn(NBATCH * NHEAD * (SDIM / 128));        // 1024, XCD-swizzled
    hipLaunchKernelGGL(attn_mfma, gattn, blk, 0, stream, Qw, Kw, Vw, gp, mask, Xo);
    hipLaunchKernelGGL(proj_mfma, gproj, blk, 0, stream, Xo, Wo, bo, out, 0);
}